// Round 3
// baseline (131.216 us; speedup 1.0000x reference)
//
#include <hip/hip_runtime.h>

#define BATCH 1024
#define N_IN 1024
#define TOTAL 18432   // 1024 + 8*2048 + 1024
#define VTOT  17408   // history entries excluding final-layer outputs
#define BLOCK 1024
#define NNEUR 17408   // 8*2048 + 1024
#define NUNITS 272    // 17408 / 64 wave-units

__device__ __forceinline__ float fast_tanh(float x) {
    // tanh(x) = 1 - 2/(1+exp(2x)) ; exact at saturation, ~1e-7 rel error
    float e = __expf(2.0f * x);
    return 1.0f - 2.0f / (1.0f + e);
}

// ---------- Preprocessing: transpose + wave-coordinated bank balancing ----------
// net gathers vals[idx] as float2 (8B): LDS bank-pair = idx mod 16. One prep
// block (64 threads = one net wave-unit of 64 consecutive neurons) permutes
// each neuron's 32 indices (sum commutative) so each slot-instruction's 64
// lanes spread evenly over the 16 bank-pairs:
//   Phase A: per-lane greedy match to target residue (slot+lane)&15 (2 slots
//            per residue per lane).
//   Phase B: leftovers placed round-by-round, each lane picking its free slot
//            with minimum shared cnt[slot][residue] (LDS atomics; benign races).
__global__ __launch_bounds__(64) void prep_kernel(const int4* __restrict__ cidx4,
                                                  int4* __restrict__ idxT) {
    __shared__ int out_s[32 * 64];   // [slot][lane] assigned index value
    __shared__ int left_s[32 * 64];  // [i][lane] leftover queue
    __shared__ int cnt[32 * 16];     // [slot][residue] load histogram
    const int lane = threadIdx.x;
    const int b = blockIdx.x;
    const int layer = (b < 256) ? (b >> 5) : 8;
    const int group = (b < 256) ? (b & 31) : (b - 256);
    const int sz    = (layer == 8) ? 1024 : 2048;
    const int ptr   = layer << 11;
    const int nloc  = group * 64 + lane;
    const int m     = ptr + nloc;

    for (int i = lane; i < 32 * 16; i += 64) cnt[i] = 0;

    const int4* src = cidx4 + (size_t)m * 8;
    int4 v[8];
    #pragma unroll
    for (int g = 0; g < 8; ++g) v[g] = src[g];
    __syncthreads();   // cnt zeroed

    const int hiFirst = (lane & 1) << 4;   // balance low/high slot preference
    unsigned slotFree = 0xFFFFFFFFu;
    int nleft = 0;
    #pragma unroll
    for (int g = 0; g < 8; ++g) {
        int comp[4] = {v[g].x, v[g].y, v[g].z, v[g].w};
        #pragma unroll
        for (int c = 0; c < 4; ++c) {
            const int id = comp[c];
            const int r  = id & 15;
            const int s1 = (r - lane) & 15;
            const int sA = s1 + hiFirst;
            const int sB = s1 + (hiFirst ^ 16);
            if (slotFree >> sA & 1u) {
                out_s[sA * 64 + lane] = id;
                slotFree &= ~(1u << sA);
                atomicAdd(&cnt[sA * 16 + r], 1);
            } else if (slotFree >> sB & 1u) {
                out_s[sB * 64 + lane] = id;
                slotFree &= ~(1u << sB);
                atomicAdd(&cnt[sB * 16 + r], 1);
            } else {
                left_s[nleft * 64 + lane] = id;
                ++nleft;
            }
        }
    }
    __syncthreads();

    // Phase B: coordinated leftover placement, one per lane per round
    for (int i = 0; i < 32; ++i) {
        unsigned long long act = __ballot(i < nleft);
        if (act == 0ull) break;              // wave-uniform
        if (i < nleft) {
            const int id = left_s[i * 64 + lane];
            const int r  = id & 15;
            unsigned f = slotFree;
            int bestS = -1, bestC = 1 << 30;
            while (f) {
                const int s = __builtin_ctz(f);
                f &= f - 1;
                const int c = cnt[s * 16 + r];
                if (c < bestC) { bestC = c; bestS = s; }
            }
            atomicAdd(&cnt[bestS * 16 + r], 1);
            out_s[bestS * 64 + lane] = id;
            slotFree &= ~(1u << bestS);
        }
        __syncthreads();
    }
    __syncthreads();

    // write transposed, coalesced: group g owns slots 4g..4g+3
    int4* dst = idxT + (size_t)ptr * 8;
    #pragma unroll
    for (int g = 0; g < 8; ++g) {
        int4 o;
        o.x = out_s[(4 * g + 0) * 64 + lane];
        o.y = out_s[(4 * g + 1) * 64 + lane];
        o.z = out_s[(4 * g + 2) * 64 + lane];
        o.w = out_s[(4 * g + 3) * 64 + lane];
        dst[(size_t)g * sz + nloc] = o;
    }
}

// ---------- Main kernel: fp32, 2 batch rows per block ----------
__global__ __launch_bounds__(BLOCK) void net_kernel_t(
    const float* __restrict__ X,
    const float* __restrict__ wptr,
    const int4* __restrict__ idxT,
    float* __restrict__ out)
{
    __shared__ float2 vals[VTOT];   // 136 KB, rows (A,B) interleaved
    const int rowA = blockIdx.x * 2;
    const float w = wptr[0];
    const int t = threadIdx.x;

    {
        const float4* xa = reinterpret_cast<const float4*>(X + (size_t)rowA * N_IN);
        const float4* xb = reinterpret_cast<const float4*>(X + (size_t)(rowA + 1) * N_IN);
        for (int i = t; i < N_IN / 4; i += BLOCK) {
            float4 a = xa[i], b = xb[i];
            vals[4 * i + 0] = make_float2(a.x, b.x);
            vals[4 * i + 1] = make_float2(a.y, b.y);
            vals[4 * i + 2] = make_float2(a.z, b.z);
            vals[4 * i + 3] = make_float2(a.w, b.w);
        }
    }
    __syncthreads();

    int off = N_IN;
    const int4* L = idxT;
    // layers 0..7 (sz = 2048): two neurons per thread, interleaved for ILP
    #pragma unroll
    for (int li = 0; li < 8; ++li) {
        const int n0 = t, n1 = t + 1024;
        float a0x = 0.f, a0y = 0.f, a1x = 0.f, a1y = 0.f;
        #pragma unroll
        for (int g = 0; g < 8; ++g) {
            int4 i0 = L[(size_t)g * 2048 + n0];
            int4 i1 = L[(size_t)g * 2048 + n1];
            float2 p = vals[i0.x], q = vals[i0.y], u = vals[i0.z], s = vals[i0.w];
            a0x += (p.x + q.x) + (u.x + s.x);
            a0y += (p.y + q.y) + (u.y + s.y);
            p = vals[i1.x]; q = vals[i1.y]; u = vals[i1.z]; s = vals[i1.w];
            a1x += (p.x + q.x) + (u.x + s.x);
            a1y += (p.y + q.y) + (u.y + s.y);
        }
        vals[off + n0] = make_float2(fast_tanh(w * a0x), fast_tanh(w * a0y));
        vals[off + n1] = make_float2(fast_tanh(w * a1x), fast_tanh(w * a1y));
        __syncthreads();
        off += 2048;
        L += (size_t)2048 * 8;
    }

    // layer 8 (sz = 1024): outputs never gathered -> write fp32 straight to out
    {
        const int n0 = t;
        float a0x = 0.f, a0y = 0.f;
        #pragma unroll
        for (int g = 0; g < 8; ++g) {
            int4 i0 = L[(size_t)g * 1024 + n0];
            float2 p = vals[i0.x], q = vals[i0.y], u = vals[i0.z], s = vals[i0.w];
            a0x += (p.x + q.x) + (u.x + s.x);
            a0y += (p.y + q.y) + (u.y + s.y);
        }
        out[(size_t)rowA * 1024 + n0]       = fast_tanh(w * a0x);
        out[(size_t)(rowA + 1) * 1024 + n0] = fast_tanh(w * a0y);
    }
}

// ---------- Fallback (ws too small): fp32 exact path, unchanged ----------
__global__ __launch_bounds__(BLOCK) void net_kernel_f(
    const float* __restrict__ X,
    const float* __restrict__ wptr,
    const int* __restrict__ cidx,
    float* __restrict__ out)
{
    __shared__ float2 vals[TOTAL];
    const int rowA = blockIdx.x * 2;
    const float w = wptr[0];
    const int t = threadIdx.x;
    {
        const float4* xa = reinterpret_cast<const float4*>(X + (size_t)rowA * N_IN);
        const float4* xb = reinterpret_cast<const float4*>(X + (size_t)(rowA + 1) * N_IN);
        for (int i = t; i < N_IN / 4; i += BLOCK) {
            float4 a = xa[i], b = xb[i];
            vals[4 * i + 0] = make_float2(a.x, b.x);
            vals[4 * i + 1] = make_float2(a.y, b.y);
            vals[4 * i + 2] = make_float2(a.z, b.z);
            vals[4 * i + 3] = make_float2(a.w, b.w);
        }
    }
    __syncthreads();
    int off = N_IN, ptr = 0;
    #pragma unroll
    for (int li = 0; li < 9; ++li) {
        const int sz = (li == 8) ? 1024 : 2048;
        for (int n = t; n < sz; n += BLOCK) {
            const int4* ip = reinterpret_cast<const int4*>(cidx + (size_t)(ptr + n) * 32);
            float sx = 0.f, sy = 0.f;
            #pragma unroll
            for (int j = 0; j < 8; ++j) {
                const int4 v = ip[j];
                float2 a = vals[v.x], b = vals[v.y], c = vals[v.z], d = vals[v.w];
                sx += (a.x + b.x) + (c.x + d.x);
                sy += (a.y + b.y) + (c.y + d.y);
            }
            vals[off + n] = make_float2(fast_tanh(w * sx), fast_tanh(w * sy));
        }
        __syncthreads();
        off += sz;
        ptr += sz;
    }
    {
        float* oA = out + (size_t)rowA * 1024;
        float* oB = out + (size_t)(rowA + 1) * 1024;
        const float2* src = vals + (TOTAL - 1024);
        for (int i = t; i < 1024; i += BLOCK) {
            float2 v = src[i];
            oA[i] = v.x;
            oB[i] = v.y;
        }
    }
}

extern "C" void kernel_launch(void* const* d_in, const int* in_sizes, int n_in,
                              void* d_out, int out_size, void* d_ws, size_t ws_size,
                              hipStream_t stream)
{
    const float* X    = (const float*)d_in[0];
    const float* w    = (const float*)d_in[1];
    const int*   cidx = (const int*)d_in[2];
    float* out = (float*)d_out;

    const size_t need = (size_t)NNEUR * 32 * sizeof(int);   // 2.23 MB
    if (ws_size >= need) {
        int4* idxT = (int4*)d_ws;
        hipLaunchKernelGGL(prep_kernel, dim3(NUNITS), dim3(64), 0, stream,
                           (const int4*)cidx, idxT);
        hipLaunchKernelGGL(net_kernel_t, dim3(BATCH / 2), dim3(BLOCK), 0, stream,
                           X, w, idxT, out);
    } else {
        hipLaunchKernelGGL(net_kernel_f, dim3(BATCH / 2), dim3(BLOCK), 0, stream,
                           X, w, cidx, out);
    }
}

// Round 4
// 125.959 us; speedup vs baseline: 1.0417x; 1.0417x over previous
//
#include <hip/hip_runtime.h>

#define BATCH 1024
#define N_IN 1024
#define TOTAL 18432   // 1024 + 8*2048 + 1024
#define VTOT  17408   // history entries excluding final-layer outputs
#define BLOCK 1024
#define NNEUR 17408   // 8*2048 + 1024
#define NUNITS 272    // 17408 / 64 wave-units

#define SCALE_T 32752.0f          // tanh-output storage scale (step 3.05e-5)
#define INV_T   (1.0f / 32752.0f)
#define SCALE_X 4094.0f           // X storage scale = SCALE_T/8 (range +-8)

__device__ __forceinline__ float fast_tanh(float x) {
    // tanh(x) = 1 - 2/(1+exp(2x)) ; exact at saturation, ~1e-7 rel error
    float e = __expf(2.0f * x);
    return 1.0f - 2.0f / (1.0f + e);
}

__device__ __forceinline__ unsigned pack16(int lo, int hi) {
    return (unsigned)(lo & 0xffff) | ((unsigned)hi << 16);
}

// ---------- Preprocessing (unchanged from R3): transpose + bank balancing ----
__global__ __launch_bounds__(64) void prep_kernel(const int4* __restrict__ cidx4,
                                                  int4* __restrict__ idxT) {
    __shared__ int out_s[32 * 64];   // [slot][lane]
    __shared__ int left_s[32 * 64];  // [i][lane]
    __shared__ int cnt[32 * 16];     // [slot][residue]
    const int lane = threadIdx.x;
    const int b = blockIdx.x;
    const int layer = (b < 256) ? (b >> 5) : 8;
    const int group = (b < 256) ? (b & 31) : (b - 256);
    const int sz    = (layer == 8) ? 1024 : 2048;
    const int ptr   = layer << 11;
    const int nloc  = group * 64 + lane;
    const int m     = ptr + nloc;

    for (int i = lane; i < 32 * 16; i += 64) cnt[i] = 0;

    const int4* src = cidx4 + (size_t)m * 8;
    int4 v[8];
    #pragma unroll
    for (int g = 0; g < 8; ++g) v[g] = src[g];
    __syncthreads();

    const int hiFirst = (lane & 1) << 4;
    unsigned slotFree = 0xFFFFFFFFu;
    int nleft = 0;
    #pragma unroll
    for (int g = 0; g < 8; ++g) {
        int comp[4] = {v[g].x, v[g].y, v[g].z, v[g].w};
        #pragma unroll
        for (int c = 0; c < 4; ++c) {
            const int id = comp[c];
            const int r  = id & 15;
            const int s1 = (r - lane) & 15;
            const int sA = s1 + hiFirst;
            const int sB = s1 + (hiFirst ^ 16);
            if (slotFree >> sA & 1u) {
                out_s[sA * 64 + lane] = id;
                slotFree &= ~(1u << sA);
                atomicAdd(&cnt[sA * 16 + r], 1);
            } else if (slotFree >> sB & 1u) {
                out_s[sB * 64 + lane] = id;
                slotFree &= ~(1u << sB);
                atomicAdd(&cnt[sB * 16 + r], 1);
            } else {
                left_s[nleft * 64 + lane] = id;
                ++nleft;
            }
        }
    }
    __syncthreads();

    for (int i = 0; i < 32; ++i) {
        unsigned long long act = __ballot(i < nleft);
        if (act == 0ull) break;
        if (i < nleft) {
            const int id = left_s[i * 64 + lane];
            const int r  = id & 15;
            unsigned f = slotFree;
            int bestS = -1, bestC = 1 << 30;
            while (f) {
                const int s = __builtin_ctz(f);
                f &= f - 1;
                const int c = cnt[s * 16 + r];
                if (c < bestC) { bestC = c; bestS = s; }
            }
            atomicAdd(&cnt[bestS * 16 + r], 1);
            out_s[bestS * 64 + lane] = id;
            slotFree &= ~(1u << bestS);
        }
        __syncthreads();
    }
    __syncthreads();

    int4* dst = idxT + (size_t)ptr * 8;
    #pragma unroll
    for (int g = 0; g < 8; ++g) {
        int4 o;
        o.x = out_s[(4 * g + 0) * 64 + lane];
        o.y = out_s[(4 * g + 1) * 64 + lane];
        o.z = out_s[(4 * g + 2) * 64 + lane];
        o.w = out_s[(4 * g + 3) * 64 + lane];
        dst[(size_t)g * sz + nloc] = o;
    }
}

// ---------- Main kernel: int16-packed, 4 batch rows per block ----------
// vals[i] = uint2{ i16(rowA)|i16(rowB)<<16, i16(rowC)|i16(rowD)<<16 }.
// tanh outputs at scale 32752 (step 3.05e-5, 16x finer than fp16).
// X entries at scale 4094 = 32752/8: unpack applies <<3 when idx < N_IN so a
// single int32 accumulator works; final value = acc/32752.
// Layer 0 (error most amplified) gathers X from an exact fp32 float4 sidecar.
__global__ __launch_bounds__(BLOCK) void net_kernel_q(
    const float* __restrict__ X,
    const float* __restrict__ wptr,
    const int4* __restrict__ idxT,
    float* __restrict__ out)
{
    __shared__ uint2 vals[VTOT];    // 136 KB
    __shared__ float4 xf32[N_IN];   // 16 KB exact X for layer 0
    const int rowA = blockIdx.x * 4;
    const float w  = wptr[0];
    const float wI = w * INV_T;
    const int t = threadIdx.x;

    {
        const float* x0 = X + (size_t)rowA * N_IN;
        float a = x0[t];
        float b = x0[N_IN + t];
        float c = x0[2 * N_IN + t];
        float d = x0[3 * N_IN + t];
        xf32[t] = make_float4(a, b, c, d);   // exact copy for layer 0
        int qa = __float2int_rn(fmaxf(-7.99f, fminf(7.99f, a)) * SCALE_X);
        int qb = __float2int_rn(fmaxf(-7.99f, fminf(7.99f, b)) * SCALE_X);
        int qc = __float2int_rn(fmaxf(-7.99f, fminf(7.99f, c)) * SCALE_X);
        int qd = __float2int_rn(fmaxf(-7.99f, fminf(7.99f, d)) * SCALE_X);
        vals[t] = make_uint2(pack16(qa, qb), pack16(qc, qd));
    }
    __syncthreads();

#define GATHX(IDX, F0, F1, F2, F3) {                      \
        float4 _x = xf32[IDX];                            \
        F0 += _x.x; F1 += _x.y; F2 += _x.z; F3 += _x.w; }

#define GATHQ(IDX, A0, A1, A2, A3) {                      \
        const int _i = (IDX);                             \
        uint2 _v = vals[_i];                              \
        const int _k = (_i < N_IN) ? 3 : 0;               \
        A0 += (((int)(_v.x << 16)) >> 16) << _k;          \
        A1 += (((int)_v.x) >> 16) << _k;                  \
        A2 += (((int)(_v.y << 16)) >> 16) << _k;          \
        A3 += (((int)_v.y) >> 16) << _k; }

#define QT(ACC) __float2int_rn(fast_tanh(wI * (float)(ACC)) * SCALE_T)

    int off = N_IN;
    const int4* L = idxT;

    // ----- layer 0: exact fp32 gathers from sidecar -----
    {
        const int n0 = t, n1 = t + 1024;
        float f0a = 0.f, f0b = 0.f, f0c = 0.f, f0d = 0.f;
        float f1a = 0.f, f1b = 0.f, f1c = 0.f, f1d = 0.f;
        #pragma unroll
        for (int g = 0; g < 8; ++g) {
            int4 i0 = L[(size_t)g * 2048 + n0];
            int4 i1 = L[(size_t)g * 2048 + n1];
            GATHX(i0.x, f0a, f0b, f0c, f0d);
            GATHX(i0.y, f0a, f0b, f0c, f0d);
            GATHX(i0.z, f0a, f0b, f0c, f0d);
            GATHX(i0.w, f0a, f0b, f0c, f0d);
            GATHX(i1.x, f1a, f1b, f1c, f1d);
            GATHX(i1.y, f1a, f1b, f1c, f1d);
            GATHX(i1.z, f1a, f1b, f1c, f1d);
            GATHX(i1.w, f1a, f1b, f1c, f1d);
        }
        int qa = __float2int_rn(fast_tanh(w * f0a) * SCALE_T);
        int qb = __float2int_rn(fast_tanh(w * f0b) * SCALE_T);
        int qc = __float2int_rn(fast_tanh(w * f0c) * SCALE_T);
        int qd = __float2int_rn(fast_tanh(w * f0d) * SCALE_T);
        vals[off + n0] = make_uint2(pack16(qa, qb), pack16(qc, qd));
        qa = __float2int_rn(fast_tanh(w * f1a) * SCALE_T);
        qb = __float2int_rn(fast_tanh(w * f1b) * SCALE_T);
        qc = __float2int_rn(fast_tanh(w * f1c) * SCALE_T);
        qd = __float2int_rn(fast_tanh(w * f1d) * SCALE_T);
        vals[off + n1] = make_uint2(pack16(qa, qb), pack16(qc, qd));
        __syncthreads();
        off += 2048;
        L += (size_t)2048 * 8;
    }

    // ----- layers 1..7: int16 gathers, int32 accumulate -----
    #pragma unroll
    for (int li = 1; li < 8; ++li) {
        const int n0 = t, n1 = t + 1024;
        int a0 = 0, b0 = 0, c0 = 0, d0 = 0;
        int a1 = 0, b1 = 0, c1 = 0, d1 = 0;
        #pragma unroll
        for (int g = 0; g < 8; ++g) {
            int4 i0 = L[(size_t)g * 2048 + n0];
            int4 i1 = L[(size_t)g * 2048 + n1];
            GATHQ(i0.x, a0, b0, c0, d0);
            GATHQ(i0.y, a0, b0, c0, d0);
            GATHQ(i0.z, a0, b0, c0, d0);
            GATHQ(i0.w, a0, b0, c0, d0);
            GATHQ(i1.x, a1, b1, c1, d1);
            GATHQ(i1.y, a1, b1, c1, d1);
            GATHQ(i1.z, a1, b1, c1, d1);
            GATHQ(i1.w, a1, b1, c1, d1);
        }
        vals[off + n0] = make_uint2(pack16(QT(a0), QT(b0)), pack16(QT(c0), QT(d0)));
        vals[off + n1] = make_uint2(pack16(QT(a1), QT(b1)), pack16(QT(c1), QT(d1)));
        __syncthreads();
        off += 2048;
        L += (size_t)2048 * 8;
    }

    // ----- layer 8: int16 gathers, fp32 output (no storage quantization) -----
    {
        const int n0 = t;
        int a0 = 0, b0 = 0, c0 = 0, d0 = 0;
        #pragma unroll
        for (int g = 0; g < 8; ++g) {
            int4 i0 = L[(size_t)g * 1024 + n0];
            GATHQ(i0.x, a0, b0, c0, d0);
            GATHQ(i0.y, a0, b0, c0, d0);
            GATHQ(i0.z, a0, b0, c0, d0);
            GATHQ(i0.w, a0, b0, c0, d0);
        }
        out[(size_t)(rowA + 0) * 1024 + n0] = fast_tanh(wI * (float)a0);
        out[(size_t)(rowA + 1) * 1024 + n0] = fast_tanh(wI * (float)b0);
        out[(size_t)(rowA + 2) * 1024 + n0] = fast_tanh(wI * (float)c0);
        out[(size_t)(rowA + 3) * 1024 + n0] = fast_tanh(wI * (float)d0);
    }
#undef GATHX
#undef GATHQ
#undef QT
}

// ---------- Fallback (ws too small): fp32 exact path, unchanged ----------
__global__ __launch_bounds__(BLOCK) void net_kernel_f(
    const float* __restrict__ X,
    const float* __restrict__ wptr,
    const int* __restrict__ cidx,
    float* __restrict__ out)
{
    __shared__ float2 vals[TOTAL];
    const int rowA = blockIdx.x * 2;
    const float w = wptr[0];
    const int t = threadIdx.x;
    {
        const float4* xa = reinterpret_cast<const float4*>(X + (size_t)rowA * N_IN);
        const float4* xb = reinterpret_cast<const float4*>(X + (size_t)(rowA + 1) * N_IN);
        for (int i = t; i < N_IN / 4; i += BLOCK) {
            float4 a = xa[i], b = xb[i];
            vals[4 * i + 0] = make_float2(a.x, b.x);
            vals[4 * i + 1] = make_float2(a.y, b.y);
            vals[4 * i + 2] = make_float2(a.z, b.z);
            vals[4 * i + 3] = make_float2(a.w, b.w);
        }
    }
    __syncthreads();
    int off = N_IN, ptr = 0;
    #pragma unroll
    for (int li = 0; li < 9; ++li) {
        const int sz = (li == 8) ? 1024 : 2048;
        for (int n = t; n < sz; n += BLOCK) {
            const int4* ip = reinterpret_cast<const int4*>(cidx + (size_t)(ptr + n) * 32);
            float sx = 0.f, sy = 0.f;
            #pragma unroll
            for (int j = 0; j < 8; ++j) {
                const int4 v = ip[j];
                float2 a = vals[v.x], b = vals[v.y], c = vals[v.z], d = vals[v.w];
                sx += (a.x + b.x) + (c.x + d.x);
                sy += (a.y + b.y) + (c.y + d.y);
            }
            vals[off + n] = make_float2(fast_tanh(w * sx), fast_tanh(w * sy));
        }
        __syncthreads();
        off += sz;
        ptr += sz;
    }
    {
        float* oA = out + (size_t)rowA * 1024;
        float* oB = out + (size_t)(rowA + 1) * 1024;
        const float2* src = vals + (TOTAL - 1024);
        for (int i = t; i < 1024; i += BLOCK) {
            float2 v = src[i];
            oA[i] = v.x;
            oB[i] = v.y;
        }
    }
}

extern "C" void kernel_launch(void* const* d_in, const int* in_sizes, int n_in,
                              void* d_out, int out_size, void* d_ws, size_t ws_size,
                              hipStream_t stream)
{
    const float* X    = (const float*)d_in[0];
    const float* w    = (const float*)d_in[1];
    const int*   cidx = (const int*)d_in[2];
    float* out = (float*)d_out;

    const size_t need = (size_t)NNEUR * 32 * sizeof(int);   // 2.23 MB
    if (ws_size >= need) {
        int4* idxT = (int4*)d_ws;
        hipLaunchKernelGGL(prep_kernel, dim3(NUNITS), dim3(64), 0, stream,
                           (const int4*)cidx, idxT);
        hipLaunchKernelGGL(net_kernel_q, dim3(BATCH / 4), dim3(BLOCK), 0, stream,
                           X, w, idxT, out);
    } else {
        hipLaunchKernelGGL(net_kernel_f, dim3(BATCH / 2), dim3(BLOCK), 0, stream,
                           X, w, cidx, out);
    }
}